// Round 5
// baseline (30.351 us; speedup 1.0000x reference)
//
#include <hip/hip_runtime.h>
#include <stdint.h>

#define K_DIM 4096
#define KW 1024          // packed words per m-row
#define M_DIM 11008
#define B_DIM 16
#define GROUP_ROWS 2752  // M / 4 groups
#define QTR_W 256        // words per row per K-quarter

typedef int v4i __attribute__((ext_vector_type(4)));

// spread low byte p (4x 2-bit fields) into 4 bytes: {p&3,(p>>2)&3,(p>>4)&3,(p>>6)&3}
__device__ __forceinline__ int spread2(int p) {
    int t = p | (p << 12);
    return (t & 0x00030003) | (((t >> 2) & 0x00030003) << 8);
}

// async global->LDS, 16 B per lane: LDS[ldsbase + lane*16] = *(gsrc_perlane)
__device__ __forceinline__ void gload_lds16(const int* g, int* l) {
    __builtin_amdgcn_global_load_lds(
        (const __attribute__((address_space(1))) unsigned int*)g,
        (__attribute__((address_space(3))) unsigned int*)l, 16, 0, 0);
}

// ---------------- kernel 1: per-row activation quantization ----------------
// 64 blocks x 256 thr: block g -> row b=g>>2, quarter qt=g&3. Each block reads the
// full row for absmax (redundant, L2-hot) then quantizes its quarter -> low latency.
__global__ __launch_bounds__(256) void quant_k(const float* __restrict__ in,
                                               int* __restrict__ qg,
                                               int* __restrict__ sumq_part,
                                               float* __restrict__ invs) {
    const int g = blockIdx.x, b = g >> 2, qt = g & 3;
    const int t = threadIdx.x, lane = t & 63, wid = t >> 6;

    const float4* row = (const float4*)(in + (size_t)b * K_DIM);
    float4 v[4];
#pragma unroll
    for (int i = 0; i < 4; ++i) v[i] = row[t + i * 256];

    float mx = 0.f;
#pragma unroll
    for (int i = 0; i < 4; ++i) {
        mx = fmaxf(mx, fabsf(v[i].x)); mx = fmaxf(mx, fabsf(v[i].y));
        mx = fmaxf(mx, fabsf(v[i].z)); mx = fmaxf(mx, fabsf(v[i].w));
    }
#pragma unroll
    for (int s = 1; s < 64; s <<= 1) mx = fmaxf(mx, __shfl_xor(mx, s, 64));

    __shared__ float wmax[4];
    __shared__ int wsum[4];
    if (lane == 0) wmax[wid] = mx;
    __syncthreads();
    const float bm = fmaxf(fmaxf(wmax[0], wmax[1]), fmaxf(wmax[2], wmax[3]));
    const float sc = 127.f / fmaxf(bm, 1e-5f);

    // thread t quantizes word qt*256 + t  ==  v[qt]
    const float4 mine = v[qt];
    float xs[4] = {mine.x, mine.y, mine.z, mine.w};
    int w = 0, ss = 0;
#pragma unroll
    for (int j = 0; j < 4; ++j) {
        int q = (int)rintf(xs[j] * sc);   // round-half-even, matches jnp.round
        q = q > 127 ? 127 : (q < -128 ? -128 : q);
        ss += q;
        w |= (q & 255) << (8 * j);
    }
    qg[b * KW + qt * QTR_W + t] = w;

#pragma unroll
    for (int s = 1; s < 64; s <<= 1) ss += __shfl_xor(ss, s, 64);
    if (lane == 0) wsum[wid] = ss;
    __syncthreads();
    if (t == 0) {
        sumq_part[b * 4 + qt] = wsum[0] + wsum[1] + wsum[2] + wsum[3];
        if (qt == 0) invs[b] = fmaxf(bm, 1e-5f) / 127.f;
    }
}

// ---------------- kernel 2: ternary GEMM via mfma_i32_16x16x64_i8 ----------------
// 688 blocks x 256 thr (4 waves); 16 m-rows/block; K in 4 quarters.
// Weights: triple-buffered LDS (3x16KB), global_load_lds DMA with pre-swizzled
// global source (LDS stays linear), 2-quarter-ahead prefetch, ONE barrier +
// counted vmcnt(4) per iteration (never 0 mid-loop). q: all 16 frags in VGPRs.
__global__ __launch_bounds__(256, 4) void gemm_k(const int* __restrict__ wp,
                                                 const int* __restrict__ qg,
                                                 const int* __restrict__ sumq_part,
                                                 const float* __restrict__ invs,
                                                 const float* __restrict__ wscale,
                                                 float* __restrict__ out) {
    __shared__ v4i bufv[3 * 1024];  // 48 KB
    int* bufi = (int*)bufv;
    const int t = threadIdx.x, lane = t & 63, wid = t >> 6;
    const int m0 = blockIdx.x * 16;
    const int lrow = lane & 15;   // b for A-frag, m-offset for B-frag
    const int lgrp = lane >> 4;   // k-group within the 64-k MFMA step

    // ---- prologue: all 16 q-fragments to regs (issued first -> oldest in vmcnt) ----
    v4i qr[16];
#pragma unroll
    for (int i = 0; i < 16; ++i) {
        const int qq = i >> 2, s = i & 3;
        qr[i] = *(const v4i*)(qg + lrow * KW + qq * QTR_W + wid * 64 + s * 16 + lgrp * 4);
    }
    // ---- DMA quarters 0 and 1 (4 rows per wave each; source pre-swizzled) ----
#pragma unroll
    for (int qq = 0; qq < 2; ++qq) {
#pragma unroll
        for (int r = 0; r < 4; ++r) {
            const int row = r * 4 + wid;
            gload_lds16(wp + (size_t)(m0 + row) * KW + qq * QTR_W + (lane ^ (row & 7)) * 4,
                        bufi + qq * 4096 + row * 256);
        }
    }

    v4i acc = {0, 0, 0, 0};

#pragma unroll
    for (int q = 0; q < 4; ++q) {
        // wait: this quarter's DMA landed (next quarter's 4 may stay in flight)
        if (q < 3) asm volatile("s_waitcnt vmcnt(4)" ::: "memory");
        else       asm volatile("s_waitcnt vmcnt(0)" ::: "memory");
        asm volatile("s_barrier" ::: "memory");
        // issue quarter q+2 into the buffer freed by quarter q-1 (safe: post-barrier)
        if (q < 2) {
            const int nb = (q + 2) % 3;
#pragma unroll
            for (int r = 0; r < 4; ++r) {
                const int row = r * 4 + wid;
                gload_lds16(wp + (size_t)(m0 + row) * KW + (q + 2) * QTR_W + (lane ^ (row & 7)) * 4,
                            bufi + nb * 4096 + row * 256);
            }
        }
        // compute quarter q from buf[q%3]
#pragma unroll
        for (int s = 0; s < 4; ++s) {
            const int c = wid * 16 + s * 4 + lgrp;
            v4i wv = bufv[(q % 3) * 1024 + lrow * 64 + (c ^ (lrow & 7))];
            v4i bb;
            bb[0] = spread2(wv[0]); bb[1] = spread2(wv[1]);
            bb[2] = spread2(wv[2]); bb[3] = spread2(wv[3]);
            acc = __builtin_amdgcn_mfma_i32_16x16x64_i8(qr[q * 4 + s], bb, acc, 0, 0, 0);
        }
    }

    // ---- cross-wave reduce via LDS (reuse bufv) ----
    __syncthreads();                 // everyone done reading buf
    bufv[wid * 64 + lane] = acc;
    __syncthreads();

    // thread t -> output (b = t>>4, m = t&15); D layout: col=lane&15, row=(lane>>4)*4+reg
    const int b = t >> 4, m = t & 15;
    const int src_lane = ((b >> 2) << 4) | m;
    const int reg = b & 3;
    int sum = bufi[(0 * 64 + src_lane) * 4 + reg] + bufi[(1 * 64 + src_lane) * 4 + reg] +
              bufi[(2 * 64 + src_lane) * 4 + reg] + bufi[(3 * 64 + src_lane) * 4 + reg];
    const int sq = sumq_part[b * 4 + 0] + sumq_part[b * 4 + 1] +
                   sumq_part[b * 4 + 2] + sumq_part[b * 4 + 3];
    const float val = (float)(sum - sq) * invs[b] * wscale[m0 / GROUP_ROWS];
    out[(size_t)b * M_DIM + m0 + m] = val;
}

extern "C" void kernel_launch(void* const* d_in, const int* in_sizes, int n_in,
                              void* d_out, int out_size, void* d_ws, size_t ws_size,
                              hipStream_t stream) {
    const float* inp    = (const float*)d_in[0];
    const int*   wp     = (const int*)d_in[1];
    const float* wscale = (const float*)d_in[2];
    float* out = (float*)d_out;

    int*   qg   = (int*)d_ws;                  // 16384 words = 64 KB
    int*   sqp  = qg + B_DIM * KW;             // 64 ints (16 rows x 4 quarter-partials)
    float* invs = (float*)(sqp + B_DIM * 4);   // 16 floats

    quant_k<<<dim3(B_DIM * 4), dim3(256), 0, stream>>>(inp, qg, sqp, invs);
    gemm_k<<<dim3(M_DIM / 16), dim3(256), 0, stream>>>(wp, qg, sqp, invs, wscale, out);
}

// Round 6
// 28.308 us; speedup vs baseline: 1.0722x; 1.0722x over previous
//
#include <hip/hip_runtime.h>
#include <stdint.h>

#define K_DIM 4096
#define KW 1024          // packed words per m-row
#define M_DIM 11008
#define B_DIM 16
#define GROUP_ROWS 2752  // M / 4 groups
#define QTR_W 256
#define LDS_ROW 1028     // words per LDS row: 256 int4 slots + 1 pad slot (bank-spread)

typedef int v4i __attribute__((ext_vector_type(4)));

// spread low byte p (4x 2-bit fields) into 4 bytes: {p&3,(p>>2)&3,(p>>4)&3,(p>>6)&3}
__device__ __forceinline__ int spread2(int p) {
    int t = p | (p << 12);
    return (t & 0x00030003) | (((t >> 2) & 0x00030003) << 8);
}

// ---------------- kernel 1: per-row activation quantization ----------------
// 64 blocks x 256 thr: block g -> row b=g>>2, quarter qt=g&3. Full-row absmax
// (redundant, L2-hot), quantize own quarter. Partial sums to sumq_part[b][qt].
__global__ __launch_bounds__(256) void quant_k(const float* __restrict__ in,
                                               int* __restrict__ qg,
                                               int* __restrict__ sumq_part,
                                               float* __restrict__ invs) {
    const int g = blockIdx.x, b = g >> 2, qt = g & 3;
    const int t = threadIdx.x, lane = t & 63, wid = t >> 6;

    const float4* row = (const float4*)(in + (size_t)b * K_DIM);
    float4 v[4];
#pragma unroll
    for (int i = 0; i < 4; ++i) v[i] = row[t + i * 256];

    float mx = 0.f;
#pragma unroll
    for (int i = 0; i < 4; ++i) {
        mx = fmaxf(mx, fabsf(v[i].x)); mx = fmaxf(mx, fabsf(v[i].y));
        mx = fmaxf(mx, fabsf(v[i].z)); mx = fmaxf(mx, fabsf(v[i].w));
    }
#pragma unroll
    for (int s = 1; s < 64; s <<= 1) mx = fmaxf(mx, __shfl_xor(mx, s, 64));

    __shared__ float wmax[4];
    __shared__ int wsum[4];
    if (lane == 0) wmax[wid] = mx;
    __syncthreads();
    const float bm = fmaxf(fmaxf(wmax[0], wmax[1]), fmaxf(wmax[2], wmax[3]));
    const float sc = 127.f / fmaxf(bm, 1e-5f);

    const float4 mine = v[qt];  // thread t quantizes word qt*256 + t
    float xs[4] = {mine.x, mine.y, mine.z, mine.w};
    int w = 0, ss = 0;
#pragma unroll
    for (int j = 0; j < 4; ++j) {
        int q = (int)rintf(xs[j] * sc);   // round-half-even, matches jnp.round
        q = q > 127 ? 127 : (q < -128 ? -128 : q);
        ss += q;
        w |= (q & 255) << (8 * j);
    }
    qg[b * KW + qt * QTR_W + t] = w;

#pragma unroll
    for (int s = 1; s < 64; s <<= 1) ss += __shfl_xor(ss, s, 64);
    if (lane == 0) wsum[wid] = ss;
    __syncthreads();
    if (t == 0) {
        sumq_part[b * 4 + qt] = wsum[0] + wsum[1] + wsum[2] + wsum[3];
        if (qt == 0) invs[b] = fmaxf(bm, 1e-5f) / 127.f;
    }
}

// ---------------- kernel 2: ternary GEMM via mfma_i32_16x16x64_i8 ----------------
// 688 blocks x 256 thr (4 waves); 16 m-rows/block; FULL K staged to LDS in ONE
// burst (64 KB in flight/block >> the ~9 KB needed to saturate the CU's HBM
// share), one barrier, then 16 MFMA steps/wave (waves split K; LDS reduce).
// Padded LDS rows (1028 words) make both staging writes and fragment reads
// conflict-free (exact 8-cycle minimum per b128 op).
__global__ __launch_bounds__(256) void gemm_k(const int* __restrict__ wp,
                                              const int* __restrict__ qg,
                                              const int* __restrict__ sumq_part,
                                              const float* __restrict__ invs,
                                              const float* __restrict__ wscale,
                                              float* __restrict__ out) {
    __shared__ int lds[16 * LDS_ROW + 8];  // 65824 B -> 2 blocks/CU
    const int t = threadIdx.x, lane = t & 63, wid = t >> 6;
    const int m0 = blockIdx.x * 16;
    const int lrow = lane & 15;   // b for A-frag, m-offset for B-frag
    const int lgrp = lane >> 4;   // k-group within the 64-k MFMA step
    const int trow = t >> 4;      // staging: row this thread fills
    const int tcol = t & 15;      // staging: slot phase

    // ---- single-shot weight burst: 16 x dwordx4 per thread, all in flight ----
    const int* wbase = wp + (size_t)(m0 + trow) * KW + tcol * 4;
    v4i wst[16];
#pragma unroll
    for (int i = 0; i < 16; ++i) wst[i] = *(const v4i*)(wbase + i * 64);
    // stage to padded LDS (compiler inserts progressive vmcnt waits per use)
#pragma unroll
    for (int i = 0; i < 16; ++i)
        *(v4i*)(lds + trow * LDS_ROW + (i * 16 + tcol) * 4) = wst[i];

    // ---- q fragments (L2-hot; waits hide under MFMA loop) ----
    v4i qr[16];
#pragma unroll
    for (int s = 0; s < 16; ++s)
        qr[s] = *(const v4i*)(qg + lrow * KW + wid * QTR_W + s * 16 + lgrp * 4);

    __syncthreads();

    // ---- 16 MFMA steps; wave wid owns k-slots wid*64 .. wid*64+63 ----
    v4i acc = {0, 0, 0, 0};
#pragma unroll
    for (int s = 0; s < 16; ++s) {
        const int slot = wid * 64 + s * 4 + lgrp;
        v4i wv = *(const v4i*)(lds + lrow * LDS_ROW + slot * 4);
        v4i bb;
        bb[0] = spread2(wv[0]); bb[1] = spread2(wv[1]);
        bb[2] = spread2(wv[2]); bb[3] = spread2(wv[3]);
        acc = __builtin_amdgcn_mfma_i32_16x16x64_i8(qr[s], bb, acc, 0, 0, 0);
    }

    // ---- cross-wave reduce via LDS (reuse staging area) ----
    __syncthreads();
    *(v4i*)(lds + (wid * 64 + lane) * 4) = acc;
    __syncthreads();

    // thread t -> output (b = t>>4, m = t&15); D layout: col=lane&15, row=(lane>>4)*4+reg
    const int b = t >> 4, m = t & 15;
    const int src_lane = ((b >> 2) << 4) | m;
    const int reg = b & 3;
    int sum = lds[(0 * 64 + src_lane) * 4 + reg] + lds[(1 * 64 + src_lane) * 4 + reg] +
              lds[(2 * 64 + src_lane) * 4 + reg] + lds[(3 * 64 + src_lane) * 4 + reg];
    const int sq = sumq_part[b * 4 + 0] + sumq_part[b * 4 + 1] +
                   sumq_part[b * 4 + 2] + sumq_part[b * 4 + 3];
    const float val = (float)(sum - sq) * invs[b] * wscale[m0 / GROUP_ROWS];
    out[(size_t)b * M_DIM + m0 + m] = val;
}

extern "C" void kernel_launch(void* const* d_in, const int* in_sizes, int n_in,
                              void* d_out, int out_size, void* d_ws, size_t ws_size,
                              hipStream_t stream) {
    const float* inp    = (const float*)d_in[0];
    const int*   wp     = (const int*)d_in[1];
    const float* wscale = (const float*)d_in[2];
    float* out = (float*)d_out;

    int*   qg   = (int*)d_ws;                  // 16384 words = 64 KB
    int*   sqp  = qg + B_DIM * KW;             // 64 ints (16 rows x 4 quarter-partials)
    float* invs = (float*)(sqp + B_DIM * 4);   // 16 floats

    quant_k<<<dim3(B_DIM * 4), dim3(256), 0, stream>>>(inp, qg, sqp, invs);
    gemm_k<<<dim3(M_DIM / 16), dim3(256), 0, stream>>>(wp, qg, sqp, invs, wscale, out);
}

// Round 7
// 24.341 us; speedup vs baseline: 1.2469x; 1.1630x over previous
//
#include <hip/hip_runtime.h>
#include <stdint.h>

#define K_DIM 4096
#define KW 1024          // packed words per m-row
#define M_DIM 11008
#define B_DIM 16
#define GROUP_ROWS 2752  // M / 4 groups
#define NTILES 688       // M / 16
#define NBLK 256         // persistent blocks: 1 per CU
#define THREADS 512

typedef int   v4i __attribute__((ext_vector_type(4)));
typedef float v4f __attribute__((ext_vector_type(4)));

// spread low byte p (4x 2-bit fields) into 4 bytes: {p&3,(p>>2)&3,(p>>4)&3,(p>>6)&3}
__device__ __forceinline__ int spread2(int p) {
    int t = p | (p << 12);
    return (t & 0x00030003) | (((t >> 2) & 0x00030003) << 8);
}

// Single persistent kernel: fused quant + ternary GEMM (mfma_i32_16x16x64_i8).
// 256 blocks x 512 threads (8 waves). Block handles tiles bid, bid+256, bid+512.
// Weights for tile i+1 prefetched into VGPRs while tile i computes from LDS ->
// ~64 KB always in flight per CU -> HBM saturated by queue depth, no rounds.
// All LDS b128 ops granule-XOR swizzled: conflict-free.
__global__ __launch_bounds__(THREADS, 2) void fused_k(const float* __restrict__ in,
                                                      const int* __restrict__ wp,
                                                      const float* __restrict__ wscale,
                                                      float* __restrict__ out) {
    __shared__ int wlds[B_DIM * KW];   // 64 KB, time-shared: q first, then weights
    __shared__ int red[8 * 64 * 4];    // 8 KB cross-wave reduce
    __shared__ float sm_invs[B_DIM];
    __shared__ int   sm_sumq[B_DIM];
    __shared__ float sm_ws[4];

    const int t = threadIdx.x, lane = t & 63, wid = t >> 6;
    const int lrow = lane & 15;        // b for A-frag, m-offset for B-frag
    const int lgrp = (lane >> 4) & 3;  // granule within 64-k MFMA step
    const int r = t >> 5, j = t & 31;  // quant/staging: row r (16), col-thread j (32)
    const int bid = blockIdx.x;

    // ---- issue tile-0 weight loads FIRST: HBM busy from cycle 0 ----
    int tile = bid;
    v4i wst[8];
    {
        const int* wb = wp + (size_t)(tile * 16 + r) * KW;
#pragma unroll
        for (int i = 0; i < 8; ++i) wst[i] = *(const v4i*)(wb + (j + i * 32) * 4);
    }

    // ---- fused quant (redundant per block; input L2-deduped per XCD) ----
    // 32 threads per row; thread j owns granules g = j + i*32 (16 k-values each).
    const float* irow = in + (size_t)r * K_DIM;
    float mx = 0.f;
#pragma unroll
    for (int i = 0; i < 8; ++i) {
        const float* gp = irow + (j + i * 32) * 16;
#pragma unroll
        for (int c = 0; c < 4; ++c) {
            v4f v = *(const v4f*)(gp + c * 4);
            mx = fmaxf(mx, fmaxf(fmaxf(fabsf(v[0]), fabsf(v[1])),
                                 fmaxf(fabsf(v[2]), fabsf(v[3]))));
        }
    }
#pragma unroll
    for (int s = 1; s < 32; s <<= 1) mx = fmaxf(mx, __shfl_xor(mx, s, 32));
    const float bm = fmaxf(mx, 1e-5f);
    const float sc = 127.f / bm;

    int ss = 0;
#pragma unroll
    for (int i = 0; i < 8; ++i) {
        const int g = j + i * 32;
        const float* gp = irow + g * 16;
        int w4[4];
#pragma unroll
        for (int c = 0; c < 4; ++c) {
            v4f v = *(const v4f*)(gp + c * 4);
            int w = 0;
#pragma unroll
            for (int e = 0; e < 4; ++e) {
                int q = (int)rintf(v[e] * sc);   // round-half-even = jnp.round
                q = q > 127 ? 127 : (q < -128 ? -128 : q);
                ss += q;
                w |= (q & 255) << (8 * e);
            }
            w4[c] = w;
        }
        *(v4i*)(wlds + r * KW + ((g ^ (r & 7)) * 4)) = *(v4i*)w4;  // q, swizzled
    }
#pragma unroll
    for (int s = 1; s < 32; s <<= 1) ss += __shfl_xor(ss, s, 32);
    if (j == 0) { sm_sumq[r] = ss; sm_invs[r] = bm / 127.f; }
    if (t < 4) sm_ws[t] = wscale[t];
    asm volatile("s_waitcnt lgkmcnt(0)" ::: "memory");
    __builtin_amdgcn_s_barrier();

    // ---- read q fragments once; reused for every tile (32 VGPR) ----
    v4i qr[8];
#pragma unroll
    for (int s = 0; s < 8; ++s) {
        const int g = wid * 32 + s * 4 + lgrp;
        qr[s] = *(const v4i*)(wlds + lrow * KW + ((g ^ (lrow & 7)) * 4));
    }
    asm volatile("s_waitcnt lgkmcnt(0)" ::: "memory");
    __builtin_amdgcn_s_barrier();   // q region free -> becomes weight buffer

    // ---- persistent tile loop ----
    for (;;) {
        const int m0 = tile * 16;
        // stage current tile's weights (compiler inserts counted vmcnt per reg)
#pragma unroll
        for (int i = 0; i < 8; ++i)
            *(v4i*)(wlds + r * KW + (((j + i * 32) ^ (r & 7)) * 4)) = wst[i];
        asm volatile("s_waitcnt lgkmcnt(0)" ::: "memory");
        __builtin_amdgcn_s_barrier();

        // prefetch next tile's weights -> in flight during compute + epilogue
        const int ntile = tile + NBLK;
        if (ntile < NTILES) {
            const int* wb = wp + (size_t)(ntile * 16 + r) * KW;
#pragma unroll
            for (int i = 0; i < 8; ++i) wst[i] = *(const v4i*)(wb + (j + i * 32) * 4);
        }

        // compute: wave wid owns k-words [wid*128, wid*128+128), 8 MFMA steps
        v4i acc = {0, 0, 0, 0};
#pragma unroll
        for (int s = 0; s < 8; ++s) {
            const int g = wid * 32 + s * 4 + lgrp;
            v4i wv = *(const v4i*)(wlds + lrow * KW + ((g ^ (lrow & 7)) * 4));
            v4i bb;
            bb[0] = spread2(wv[0]); bb[1] = spread2(wv[1]);
            bb[2] = spread2(wv[2]); bb[3] = spread2(wv[3]);
            acc = __builtin_amdgcn_mfma_i32_16x16x64_i8(qr[s], bb, acc, 0, 0, 0);
        }

        // cross-wave reduce (8 K-partials) + epilogue
        *(v4i*)(red + (wid * 64 + lane) * 4) = acc;
        asm volatile("s_waitcnt lgkmcnt(0)" ::: "memory");
        __builtin_amdgcn_s_barrier();
        if (t < 256) {
            const int b = t >> 4, m = t & 15;
            const int sl = ((b >> 2) << 4) | m;   // D layout: col=lane&15, row=(lane>>4)*4+reg
            const int rg = b & 3;
            int sum = 0;
#pragma unroll
            for (int w8 = 0; w8 < 8; ++w8) sum += red[(w8 * 64 + sl) * 4 + rg];
            const float val = (float)(sum - sm_sumq[b]) * sm_invs[b] * sm_ws[m0 / GROUP_ROWS];
            out[(size_t)b * M_DIM + m0 + m] = val;
        }
        if (ntile >= NTILES) break;
        tile = ntile;
        // next iteration's staging barrier orders epilogue red-reads before red re-writes
    }
}

extern "C" void kernel_launch(void* const* d_in, const int* in_sizes, int n_in,
                              void* d_out, int out_size, void* d_ws, size_t ws_size,
                              hipStream_t stream) {
    const float* inp    = (const float*)d_in[0];
    const int*   wp     = (const int*)d_in[1];
    const float* wscale = (const float*)d_in[2];
    float* out = (float*)d_out;

    fused_k<<<dim3(NBLK), dim3(THREADS), 0, stream>>>(inp, wp, wscale, out);
}

// Round 8
// 19.943 us; speedup vs baseline: 1.5219x; 1.2205x over previous
//
#include <hip/hip_runtime.h>
#include <stdint.h>

#define K_DIM 4096
#define KW 1024          // packed words per m-row
#define M_DIM 11008
#define B_DIM 16
#define GROUP_ROWS 2752  // M / 4 groups

typedef int v4i __attribute__((ext_vector_type(4)));

// spread low byte p (4x 2-bit fields) into 4 bytes: {p&3,(p>>2)&3,(p>>4)&3,(p>>6)&3}
__device__ __forceinline__ int spread2(int p) {
    int t = p | (p << 12);
    return (t & 0x00030003) | (((t >> 2) & 0x00030003) << 8);
}

// ---------------- kernel 1: per-row activation quantization ----------------
// 16 blocks x 1024 threads; thread t quantizes 4 floats -> one packed int32 word.
__global__ __launch_bounds__(1024) void quant_k(const float* __restrict__ in,
                                                int* __restrict__ qg,
                                                int* __restrict__ sumq,
                                                float* __restrict__ invs) {
    const int b = blockIdx.x, t = threadIdx.x;
    const int lane = t & 63, wid = t >> 6;  // 16 waves

    float4 v = ((const float4*)(in + (size_t)b * K_DIM))[t];
    float mx = fmaxf(fmaxf(fabsf(v.x), fabsf(v.y)), fmaxf(fabsf(v.z), fabsf(v.w)));
#pragma unroll
    for (int s = 1; s < 64; s <<= 1) mx = fmaxf(mx, __shfl_xor(mx, s, 64));

    __shared__ float wmax[16];
    __shared__ int wsum[16];
    if (lane == 0) wmax[wid] = mx;
    __syncthreads();
    float bm = wmax[0];
#pragma unroll
    for (int i = 1; i < 16; ++i) bm = fmaxf(bm, wmax[i]);
    const float sc = 127.f / fmaxf(bm, 1e-5f);

    float xs[4] = {v.x, v.y, v.z, v.w};
    int w = 0, ss = 0;
#pragma unroll
    for (int j = 0; j < 4; ++j) {
        int q = (int)rintf(xs[j] * sc);   // round-half-even, matches jnp.round
        q = q > 127 ? 127 : (q < -128 ? -128 : q);
        ss += q;
        w |= (q & 255) << (8 * j);
    }
    qg[b * KW + t] = w;

#pragma unroll
    for (int s = 1; s < 64; s <<= 1) ss += __shfl_xor(ss, s, 64);
    if (lane == 0) wsum[wid] = ss;
    __syncthreads();
    if (t == 0) {
        int tot = 0;
#pragma unroll
        for (int i = 0; i < 16; ++i) tot += wsum[i];
        sumq[b] = tot;
        invs[b] = fmaxf(bm, 1e-5f) / 127.f;
    }
}

// ---------------- kernel 2: ternary GEMM via mfma_i32_16x16x64_i8 ----------------
// 688 blocks x 256 thr (4 waves). Waves are FULLY DECOUPLED in the hot path:
// wave wid owns k-words [wid*256,(wid+1)*256) of all 16 rows (16 KB), loaded in
// ONE burst of 16 NON-TEMPORAL dwordx4 (bypass L1/L3 allocate), staged to its
// private LDS region with per-wave counted vmcnt + lgkmcnt only — no barriers
// until the final cross-wave reduce. q-fragments issued FIRST so the counted
// vmcnt waits stay progressive (chunk c stageable at vmcnt(12-4c)).
__global__ __launch_bounds__(256, 2) void gemm_k(const int* __restrict__ wp,
                                                 const int* __restrict__ qg,
                                                 const int* __restrict__ sumq,
                                                 const float* __restrict__ invs,
                                                 const float* __restrict__ wscale,
                                                 float* __restrict__ out) {
    __shared__ v4i wbuf[4 * 1024];  // 64 KB: wave wid -> [wid*1024, wid*1024+1024)
    __shared__ int red[4 * 64 * 4]; // 4 KB
    const int t = threadIdx.x, lane = t & 63, wid = t >> 6;
    const int m0 = blockIdx.x * 16;
    const int lrow = lane & 15;   // b for A-frag, m-offset for B-frag, col for loads
    const int lgrp = lane >> 4;   // k-group / staging row phase

    // ---- q fragments first (L2-hot, oldest in vmcnt queue) ----
    v4i qr[16];
#pragma unroll
    for (int s = 0; s < 16; ++s)
        qr[s] = *(const v4i*)(qg + lrow * KW + wid * 256 + s * 16 + lgrp * 4);

    // ---- single burst: 16 NT loads, whole K-quarter (16 KB/wave) in flight ----
    v4i wst[16];
#pragma unroll
    for (int c = 0; c < 4; ++c)
#pragma unroll
        for (int i = 0; i < 4; ++i) {
            const int row = i * 4 + lgrp;
            wst[c * 4 + i] = __builtin_nontemporal_load(
                (const v4i*)(wp + (size_t)(m0 + row) * KW + wid * 256 + c * 64 + lrow * 4));
        }

    // ---- per-wave staged compute: chunk c ready at counted vmcnt, no barriers ----
    v4i acc = {0, 0, 0, 0};
#pragma unroll
    for (int c = 0; c < 4; ++c) {
#pragma unroll
        for (int i = 0; i < 4; ++i) {
            const int row = i * 4 + lgrp;
            wbuf[wid * 1024 + c * 256 + row * 16 + (lrow ^ (row & 7))] = wst[c * 4 + i];
        }
        asm volatile("s_waitcnt lgkmcnt(0)" ::: "memory");  // own writes visible (same wave)
#pragma unroll
        for (int sp = 0; sp < 4; ++sp) {
            v4i wv = wbuf[wid * 1024 + c * 256 + lrow * 16 + ((sp * 4 + lgrp) ^ (lrow & 7))];
            v4i bb;
            bb[0] = spread2(wv[0]); bb[1] = spread2(wv[1]);
            bb[2] = spread2(wv[2]); bb[3] = spread2(wv[3]);
            acc = __builtin_amdgcn_mfma_i32_16x16x64_i8(qr[c * 4 + sp], bb, acc, 0, 0, 0);
        }
    }

    // ---- cross-wave reduce (only barriers in the kernel) ----
    *(v4i*)(red + (wid * 64 + lane) * 4) = acc;
    __syncthreads();

    // thread t -> output (b = t>>4, m = t&15); D layout: col=lane&15, row=(lane>>4)*4+reg
    const int b = t >> 4, m = t & 15;
    const int src_lane = ((b >> 2) << 4) | m;
    const int reg = b & 3;
    int sum = red[(0 * 64 + src_lane) * 4 + reg] + red[(1 * 64 + src_lane) * 4 + reg] +
              red[(2 * 64 + src_lane) * 4 + reg] + red[(3 * 64 + src_lane) * 4 + reg];
    const float val = (float)(sum - sumq[b]) * invs[b] * wscale[m0 / GROUP_ROWS];
    out[(size_t)b * M_DIM + m0 + m] = val;
}

extern "C" void kernel_launch(void* const* d_in, const int* in_sizes, int n_in,
                              void* d_out, int out_size, void* d_ws, size_t ws_size,
                              hipStream_t stream) {
    const float* inp    = (const float*)d_in[0];
    const int*   wp     = (const int*)d_in[1];
    const float* wscale = (const float*)d_in[2];
    float* out = (float*)d_out;

    int*   qg   = (int*)d_ws;               // 16384 words = 64 KB
    int*   sumq = qg + B_DIM * KW;          // 16 ints
    float* invs = (float*)(sumq + B_DIM);   // 16 floats

    quant_k<<<dim3(B_DIM), dim3(1024), 0, stream>>>(inp, qg, sumq, invs);
    gemm_k<<<dim3(M_DIM / 16), dim3(256), 0, stream>>>(wp, qg, sumq, invs, wscale, out);
}